// Round 4
// baseline (221.204 us; speedup 1.0000x reference)
//
#include <hip/hip_runtime.h>
#include <hip/hip_fp16.h>

constexpr int N = 50000;        // nodes
constexpr int D = 64;           // feature dim
constexpr int E = 1600000;      // edges
constexpr int NBUCK = (N + 127) / 128;   // 391 buckets of 128 nodes (dst>>7)
constexpr int CAP = 4608;                // bucket window capacity (mean 4092, +8 sigma)
constexpr int BTHREADS = 512;
constexpr int BBLOCKS = 512;             // 2 blocks/CU exactly
constexpr int EPB = E / BBLOCKS;         // 3125 edges per block (exact)
constexpr int CPT = (EPB + BTHREADS - 1) / BTHREADS;  // 7

// ---------------------------------------------------------------------------
// K0: zero deg[] and init per-bucket window cursors
__global__ void k_init(int* __restrict__ cursor, int* __restrict__ deg) {
    int i = blockIdx.x * 512 + threadIdx.x;
    if (i < N) deg[i] = 0;
    if (i < NBUCK) cursor[i] = i * CAP;
}

// K1: privatized counting-sort scatter -> fixed-capacity bucket windows.
// packed = dst<<16 | src (both < 65536); bucket = packed>>23.
// NEW: also counts per-node in-degree via fire-and-forget global atomics
// (frees the GEMM from depending on the CSR stage).
__global__ void k_bucket(const int* __restrict__ src, const int* __restrict__ dst,
                         int* __restrict__ cursor, unsigned* __restrict__ packed,
                         int* __restrict__ deg) {
    __shared__ int lh[NBUCK];
    __shared__ int scanI[NBUCK];         // inclusive prefix over buckets
    __shared__ int wsum[8];
    __shared__ int lb[NBUCK];
    __shared__ unsigned stage[EPB];      // 12.5 KB
    int tid = threadIdx.x;
    if (tid < NBUCK) lh[tid] = 0;
    __syncthreads();
    int base_e = blockIdx.x * EPB;
    unsigned pk[CPT];
    int bn[CPT], rk[CPT];
#pragma unroll
    for (int i = 0; i < CPT; ++i) {
        int idx = i * BTHREADS + tid;
        if (idx < EPB) {
            int e = base_e + idx;
            int d = dst[e];
            int s = src[e];
            bn[i] = d >> 7;
            pk[i] = ((unsigned)d << 16) | (unsigned)s;
            rk[i] = atomicAdd(&lh[bn[i]], 1);
            atomicAdd(&deg[d], 1);       // fire-and-forget, no return value
        } else bn[i] = -1;
    }
    __syncthreads();
    // hierarchical inclusive scan of lh[0..NBUCK) into scanI
    int w = tid >> 6, l = tid & 63;
    int v = (tid < NBUCK) ? lh[tid] : 0;
    for (int off = 1; off < 64; off <<= 1) {
        int t = __shfl_up(v, off, 64);
        if (l >= off) v += t;
    }
    if (tid < NBUCK) scanI[tid] = v;
    if (l == 63) wsum[w] = v;
    __syncthreads();
    if (tid < 64) {                      // wave 0 scans the 8 wave sums
        int s = (tid < 8) ? wsum[tid] : 0;
        for (int off = 1; off < 8; off <<= 1) {
            int t = __shfl_up(s, off, 64);
            if (tid >= off) s += t;
        }
        if (tid < 8) wsum[tid] = s;
    }
    __syncthreads();
    if (tid < NBUCK && w > 0) scanI[tid] += wsum[w - 1];
    if (tid < NBUCK) {
        int c = lh[tid];
        lb[tid] = c ? atomicAdd(&cursor[tid], c) : 0;   // one global atomic/bucket/block
    }
    __syncthreads();
#pragma unroll
    for (int i = 0; i < CPT; ++i) {
        if (bn[i] >= 0) {
            int eb = (bn[i] == 0) ? 0 : scanI[bn[i] - 1];
            stage[eb + rk[i]] = pk[i];   // LDS scatter into bucket-sorted order
        }
    }
    __syncthreads();
    for (int j = tid; j < EPB; j += BTHREADS) {
        unsigned vv = stage[j];
        int bk = vv >> 23;               // dst>>7
        int eb = (bk == 0) ? 0 : scanI[bk - 1];
        packed[lb[bk] + (j - eb)] = vv;  // contiguous within each chunk
    }
}

// K2 (register-tiled LDS GEMM): h2[row][d] = (x@W)[row][d] * rsqrt(deg[row]), fp16.
// 64x64 tile per block, 256 threads, 4x4 register tile per thread.
// (round-3 verified version; norm[] replaced by inline rsqrt of deg[])
__global__ __launch_bounds__(256)
void k_gemm(const float* __restrict__ x, const float* __restrict__ W,
            const int* __restrict__ deg, __half* __restrict__ h2) {
    __shared__ float xT[64 * 68];        // xT[k*68 + r] = x[rowbase+r][k]  (17 KB)
    __shared__ float Wl[64 * 64];        // Wl[k*64 + d] = W[k][d]          (16 KB)
    int tid = threadIdx.x;
    int rowbase = blockIdx.x * 64;
    // load W: 256 threads x 4 float4
    {
        const float4* W4 = (const float4*)W;
        float4* Wl4 = (float4*)Wl;
#pragma unroll
        for (int i = 0; i < 4; ++i)
            Wl4[i * 256 + tid] = W4[i * 256 + tid];
    }
    // load x tile transposed: thread loads 16 floats of row rr
    {
        int rr = tid >> 2;
        int c0 = (tid & 3) * 16;
        int row = rowbase + rr;
        if (row >= N) row = N - 1;       // clamp (stores are guarded)
        const float4* xr = (const float4*)(x + (size_t)row * 64 + c0);
#pragma unroll
        for (int i = 0; i < 4; ++i) {
            float4 v = xr[i];
            int c = c0 + i * 4;
            xT[(c + 0) * 68 + rr] = v.x;
            xT[(c + 1) * 68 + rr] = v.y;
            xT[(c + 2) * 68 + rr] = v.z;
            xT[(c + 3) * 68 + rr] = v.w;
        }
    }
    __syncthreads();
    int tx = tid & 15;                   // col group: cols tx*4 .. +3
    int ty = tid >> 4;                   // row group: rows ty*4 .. +3
    float acc[4][4] = {};
#pragma unroll 8
    for (int k = 0; k < 64; ++k) {
        float4 xv = *(const float4*)&xT[k * 68 + ty * 4];
        float4 wv = *(const float4*)&Wl[k * 64 + tx * 4];
        acc[0][0] = fmaf(xv.x, wv.x, acc[0][0]);
        acc[0][1] = fmaf(xv.x, wv.y, acc[0][1]);
        acc[0][2] = fmaf(xv.x, wv.z, acc[0][2]);
        acc[0][3] = fmaf(xv.x, wv.w, acc[0][3]);
        acc[1][0] = fmaf(xv.y, wv.x, acc[1][0]);
        acc[1][1] = fmaf(xv.y, wv.y, acc[1][1]);
        acc[1][2] = fmaf(xv.y, wv.z, acc[1][2]);
        acc[1][3] = fmaf(xv.y, wv.w, acc[1][3]);
        acc[2][0] = fmaf(xv.z, wv.x, acc[2][0]);
        acc[2][1] = fmaf(xv.z, wv.y, acc[2][1]);
        acc[2][2] = fmaf(xv.z, wv.z, acc[2][2]);
        acc[2][3] = fmaf(xv.z, wv.w, acc[2][3]);
        acc[3][0] = fmaf(xv.w, wv.x, acc[3][0]);
        acc[3][1] = fmaf(xv.w, wv.y, acc[3][1]);
        acc[3][2] = fmaf(xv.w, wv.z, acc[3][2]);
        acc[3][3] = fmaf(xv.w, wv.w, acc[3][3]);
    }
#pragma unroll
    for (int i = 0; i < 4; ++i) {
        int row = rowbase + ty * 4 + i;
        if (row < N) {
            int dg = deg[row];
            float nr = dg ? rsqrtf((float)dg) : 0.0f;
            __half2 p0 = __floats2half2_rn(acc[i][0] * nr, acc[i][1] * nr);
            __half2 p1 = __floats2half2_rn(acc[i][2] * nr, acc[i][3] * nr);
            __half2* dst2 = (__half2*)(h2 + (size_t)row * 64 + tx * 4);
            dst2[0] = p0;
            dst2[1] = p1;
        }
    }
}

// K3 (NEW fused sort+aggregate): one 1024-thread block per 128-node bucket.
// Phase 1: single-pass in-LDS counting sort of the bucket window — the rank
// returned by the histogram atomicAdd IS the stable slot (no second pass, no
// global csr round-trip). Phase 2: wave-per-node shfl-gather (verified
// round-3 k_aggregate structure) reading indices from the LDS stage;
// dst-norm comes from the in-LDS histogram. 391 blocks at 2/CU -> all
// co-resident, no dispatch tail.
__global__ __launch_bounds__(1024, 8)
void k_fused(const int* __restrict__ cursor, const unsigned* __restrict__ packed,
             const __half* __restrict__ h2, const float* __restrict__ bias,
             float* __restrict__ out) {
    __shared__ int cnt[128];             // per-node degree (histogram)
    __shared__ int rowoff[128];          // exclusive start within stage
    __shared__ int rowend_s[128];        // inclusive end within stage
    __shared__ unsigned short stage[CAP];   // 9 KB node-sorted src list
    int b = blockIdx.x, tid = threadIdx.x;
    if (tid < 128) cnt[tid] = 0;
    __syncthreads();
    int beg = b * CAP;
    int m = cursor[b] - beg;             // edges in this bucket (<= CAP)
    unsigned pk[5];
    int rk[5], dd[5];
#pragma unroll
    for (int it = 0; it < 5; ++it) {     // CAP/1024 = 4.5 -> 5 iterations max
        int j = it * 1024 + tid;
        if (j < m) {
            unsigned p = packed[beg + j];
            int d = (p >> 16) & 127;
            dd[it] = d;
            pk[it] = p;
            rk[it] = atomicAdd(&cnt[d], 1);   // rank = stable slot
        } else dd[it] = -1;
    }
    __syncthreads();
    if (tid < 64) {                      // wave 0: 2 bins/lane inclusive scan
        int a = cnt[2 * tid], c1 = cnt[2 * tid + 1];
        int s = a + c1;
        for (int off = 1; off < 64; off <<= 1) {
            int t = __shfl_up(s, off, 64);
            if (tid >= off) s += t;
        }
        rowend_s[2 * tid + 1] = s;       // incl(2t+1)
        rowend_s[2 * tid]     = s - c1;  // incl(2t)
        rowoff[2 * tid + 1]   = s - c1;  // excl(2t+1)
        rowoff[2 * tid]       = s - c1 - a;  // excl(2t)
    }
    __syncthreads();
#pragma unroll
    for (int it = 0; it < 5; ++it)
        if (dd[it] >= 0)
            stage[rowoff[dd[it]] + rk[it]] = (unsigned short)(pk[it] & 0xFFFFu);
    __syncthreads();
    // ---- phase 2: wave per node, 8 consecutive nodes per wave ----
    int wv = tid >> 6, lane = tid & 63;
    int half = lane >> 5;                // which edge of the pair
    int fl = lane & 31;                  // feature-pair index
    const __half2* h2v = (const __half2*)h2;   // row stride 32
    float2 bs = ((const float2*)bias)[fl];
    for (int i = 0; i < 8; ++i) {
        int r = wv * 8 + i;
        int node = b * 128 + r;
        int rb = rowoff[r];
        int re = rowend_s[r];
        int deg = re - rb;
        int myidx = (rb + lane < re) ? (int)stage[rb + lane] : 0;
        int window = deg < 64 ? deg : 64;    // wave-uniform
        int npair = window >> 1;
        float ax = 0.0f, ay = 0.0f, bx = 0.0f, by = 0.0f;
        int p = 0;
        for (; p + 7 < npair; p += 8) {      // 16 edges / iter, 8 loads in flight
            int s0 = __shfl(myidx, 2 * p + half, 64);
            int s1 = __shfl(myidx, 2 * p + 2 + half, 64);
            int s2 = __shfl(myidx, 2 * p + 4 + half, 64);
            int s3 = __shfl(myidx, 2 * p + 6 + half, 64);
            int s4 = __shfl(myidx, 2 * p + 8 + half, 64);
            int s5 = __shfl(myidx, 2 * p + 10 + half, 64);
            int s6 = __shfl(myidx, 2 * p + 12 + half, 64);
            int s7 = __shfl(myidx, 2 * p + 14 + half, 64);
            float2 v0 = __half22float2(h2v[s0 * 32 + fl]);
            float2 v1 = __half22float2(h2v[s1 * 32 + fl]);
            float2 v2 = __half22float2(h2v[s2 * 32 + fl]);
            float2 v3 = __half22float2(h2v[s3 * 32 + fl]);
            float2 v4 = __half22float2(h2v[s4 * 32 + fl]);
            float2 v5 = __half22float2(h2v[s5 * 32 + fl]);
            float2 v6 = __half22float2(h2v[s6 * 32 + fl]);
            float2 v7 = __half22float2(h2v[s7 * 32 + fl]);
            ax += (v0.x + v2.x) + (v4.x + v6.x);
            ay += (v0.y + v2.y) + (v4.y + v6.y);
            bx += (v1.x + v3.x) + (v5.x + v7.x);
            by += (v1.y + v3.y) + (v5.y + v7.y);
        }
        for (; p + 3 < npair; p += 4) {      // 8 edges per iteration
            int s0 = __shfl(myidx, 2 * p + half, 64);
            int s1 = __shfl(myidx, 2 * p + 2 + half, 64);
            int s2 = __shfl(myidx, 2 * p + 4 + half, 64);
            int s3 = __shfl(myidx, 2 * p + 6 + half, 64);
            float2 v0 = __half22float2(h2v[s0 * 32 + fl]);
            float2 v1 = __half22float2(h2v[s1 * 32 + fl]);
            float2 v2 = __half22float2(h2v[s2 * 32 + fl]);
            float2 v3 = __half22float2(h2v[s3 * 32 + fl]);
            ax += v0.x + v2.x;  ay += v0.y + v2.y;
            bx += v1.x + v3.x;  by += v1.y + v3.y;
        }
        for (; p < npair; ++p) {             // pair tail (uniform trip count)
            int s = __shfl(myidx, 2 * p + half, 64);
            float2 v = __half22float2(h2v[s * 32 + fl]);
            ax += v.x;  ay += v.y;
        }
        if (window & 1) {                    // wave-uniform: all lanes shfl
            int s = __shfl(myidx, window - 1, 64);
            float2 v = __half22float2(h2v[s * 32 + fl]);
            if (half == 0) { ax += v.x;  ay += v.y; }
        }
        if (deg > 64) {                      // rare fallback, LDS index reads
            int j = rb + 64;
            for (; j + 1 < re; j += 2) {
                int s = stage[j + half];
                float2 v = __half22float2(h2v[s * 32 + fl]);
                ax += v.x;  ay += v.y;
            }
            if (j < re) {
                int s = stage[j];
                float2 v = __half22float2(h2v[s * 32 + fl]);
                if (half == 0) { ax += v.x;  ay += v.y; }
            }
        }
        ax += bx;  ay += by;
        ax += __shfl_xor(ax, 32, 64);        // combine the two half-waves
        ay += __shfl_xor(ay, 32, 64);
        if (half == 0 && node < N) {
            float nrm = deg ? rsqrtf((float)deg) : 0.0f;
            float vx = ax * nrm + bs.x;
            float vy = ay * nrm + bs.y;
            float2 o;
            o.x = fmaxf(vx, 0.0f) + log1pf(expf(-fabsf(vx)));
            o.y = fmaxf(vy, 0.0f) + log1pf(expf(-fabsf(vy)));
            ((float2*)out)[node * 32 + fl] = o;
        }
    }
}

extern "C" void kernel_launch(void* const* d_in, const int* in_sizes, int n_in,
                              void* d_out, int out_size, void* d_ws, size_t ws_size,
                              hipStream_t stream) {
    // inputs: t(f32,1), x(f32,N*D), weight(f32,D*D), bias(f32,D), src(i32,E), dst(i32,E)
    const float* x    = (const float*)d_in[1];
    const float* W    = (const float*)d_in[2];
    const float* bias = (const float*)d_in[3];
    const int* src = (const int*)d_in[4];
    const int* dst = (const int*)d_in[5];
    float* out = (float*)d_out;

    // workspace layout (~13.8 MB; poisoned every call — every buffer is
    // fully written before it is read: deg/cursor by k_init, packed windows
    // only read up to cursor[b], h2 fully written by k_gemm)
    char* ws = (char*)d_ws;
    __half*   h2     = (__half*)(ws);                   // N*D*2      = 6.4 MB
    unsigned* packed = (unsigned*)(ws + 6400000);       // NBUCK*CAP*4 = 7.21 MB
    int*      deg    = (int*)(ws + 13606912);           // N*4
    int*      cursor = (int*)(ws + 13806912);           // NBUCK*4

    k_init  <<<(N + 511) / 512, 512, 0, stream>>>(cursor, deg);
    k_bucket<<<BBLOCKS, BTHREADS, 0, stream>>>(src, dst, cursor, packed, deg);
    k_gemm  <<<(N + 63) / 64, 256, 0, stream>>>(x, W, deg, h2);
    k_fused <<<NBUCK, 1024, 0, stream>>>(cursor, packed, h2, bias, out);
}

// Round 5
// 176.601 us; speedup vs baseline: 1.2526x; 1.2526x over previous
//
#include <hip/hip_runtime.h>
#include <hip/hip_fp16.h>

constexpr int N = 50000;        // nodes
constexpr int D = 64;           // feature dim
constexpr int E = 1600000;      // edges
constexpr int NBUCK = (N + 127) / 128;   // 391 buckets of 128 nodes (dst>>7)
constexpr int CAP = 4608;                // bucket window capacity (mean 4092)
constexpr int BTHREADS = 512;
constexpr int BBLOCKS = 512;             // 2 blocks/CU exactly
constexpr int EPB = E / BBLOCKS;         // 3125 edges per block (exact)
constexpr int CPT = (EPB + BTHREADS - 1) / BTHREADS;  // 7

// ---------------------------------------------------------------------------
// K0: init per-bucket window cursors (cursor[b] = b*CAP)
__global__ void k_init(int* __restrict__ cursor) {
    int t = threadIdx.x;
    if (t < NBUCK) cursor[t] = t * CAP;
}

// K1: privatized counting-sort scatter -> fixed-capacity bucket windows.
// packed = dst<<16 | src (both < 65536); bucket = packed>>23.
// (verified round-3 version, NO deg atomics — round-4 showed scattered
// global atomics cost ~35 µs + 10x write amplification)
__global__ void k_bucket(const int* __restrict__ src, const int* __restrict__ dst,
                         int* __restrict__ cursor, unsigned* __restrict__ packed) {
    __shared__ int lh[NBUCK];
    __shared__ int scanI[NBUCK];         // inclusive prefix over buckets
    __shared__ int wsum[8];
    __shared__ int lb[NBUCK];
    __shared__ unsigned stage[EPB];      // 12.5 KB
    int tid = threadIdx.x;
    if (tid < NBUCK) lh[tid] = 0;
    __syncthreads();
    int base_e = blockIdx.x * EPB;
    unsigned pk[CPT];
    int bn[CPT], rk[CPT];
#pragma unroll
    for (int i = 0; i < CPT; ++i) {
        int idx = i * BTHREADS + tid;
        if (idx < EPB) {
            int e = base_e + idx;
            int d = dst[e];
            int s = src[e];
            bn[i] = d >> 7;
            pk[i] = ((unsigned)d << 16) | (unsigned)s;
            rk[i] = atomicAdd(&lh[bn[i]], 1);
        } else bn[i] = -1;
    }
    __syncthreads();
    // hierarchical inclusive scan of lh[0..NBUCK) into scanI
    int w = tid >> 6, l = tid & 63;
    int v = (tid < NBUCK) ? lh[tid] : 0;
    for (int off = 1; off < 64; off <<= 1) {
        int t = __shfl_up(v, off, 64);
        if (l >= off) v += t;
    }
    if (tid < NBUCK) scanI[tid] = v;
    if (l == 63) wsum[w] = v;
    __syncthreads();
    if (tid < 64) {                      // wave 0 scans the 8 wave sums
        int s = (tid < 8) ? wsum[tid] : 0;
        for (int off = 1; off < 8; off <<= 1) {
            int t = __shfl_up(s, off, 64);
            if (tid >= off) s += t;
        }
        if (tid < 8) wsum[tid] = s;
    }
    __syncthreads();
    if (tid < NBUCK && w > 0) scanI[tid] += wsum[w - 1];
    if (tid < NBUCK) {
        int c = lh[tid];
        lb[tid] = c ? atomicAdd(&cursor[tid], c) : 0;   // one global atomic/bucket/block
    }
    __syncthreads();
#pragma unroll
    for (int i = 0; i < CPT; ++i) {
        if (bn[i] >= 0) {
            int eb = (bn[i] == 0) ? 0 : scanI[bn[i] - 1];
            stage[eb + rk[i]] = pk[i];   // LDS scatter into bucket-sorted order
        }
    }
    __syncthreads();
    for (int j = tid; j < EPB; j += BTHREADS) {
        unsigned vv = stage[j];
        int bk = vv >> 23;               // dst>>7
        int eb = (bk == 0) ? 0 : scanI[bk - 1];
        packed[lb[bk] + (j - eb)] = vv;  // contiguous within each chunk
    }
}

// K2: per-bucket degree histogram -> norm (round-1 verified version).
// LDS-private 128-bin histogram of the bucket window; no global atomics.
__global__ void k_norm(const int* __restrict__ cursor, const unsigned* __restrict__ packed,
                       float* __restrict__ norm) {
    __shared__ int cnt[128];
    int b = blockIdx.x, tid = threadIdx.x;
    if (tid < 128) cnt[tid] = 0;
    __syncthreads();
    int beg = b * CAP;
    int m = cursor[b] - beg;
    for (int j = tid; j < m; j += 256)
        atomicAdd(&cnt[(packed[beg + j] >> 16) & 127], 1);
    __syncthreads();
    if (tid < 128) {
        int node = b * 128 + tid;
        if (node < N)
            norm[node] = cnt[tid] ? rsqrtf((float)cnt[tid]) : 0.0f;
    }
}

// K3 (register-tiled LDS GEMM): h2[row][d] = (x@W)[row][d] * norm[row], fp16.
// (verified round-3 version)
__global__ __launch_bounds__(256)
void k_gemm(const float* __restrict__ x, const float* __restrict__ W,
            const float* __restrict__ norm, __half* __restrict__ h2) {
    __shared__ float xT[64 * 68];        // xT[k*68 + r] = x[rowbase+r][k]  (17 KB)
    __shared__ float Wl[64 * 64];        // Wl[k*64 + d] = W[k][d]          (16 KB)
    int tid = threadIdx.x;
    int rowbase = blockIdx.x * 64;
    {
        const float4* W4 = (const float4*)W;
        float4* Wl4 = (float4*)Wl;
#pragma unroll
        for (int i = 0; i < 4; ++i)
            Wl4[i * 256 + tid] = W4[i * 256 + tid];
    }
    {
        int rr = tid >> 2;
        int c0 = (tid & 3) * 16;
        int row = rowbase + rr;
        if (row >= N) row = N - 1;       // clamp (stores are guarded)
        const float4* xr = (const float4*)(x + (size_t)row * 64 + c0);
#pragma unroll
        for (int i = 0; i < 4; ++i) {
            float4 v = xr[i];
            int c = c0 + i * 4;
            xT[(c + 0) * 68 + rr] = v.x;
            xT[(c + 1) * 68 + rr] = v.y;
            xT[(c + 2) * 68 + rr] = v.z;
            xT[(c + 3) * 68 + rr] = v.w;
        }
    }
    __syncthreads();
    int tx = tid & 15;                   // col group: cols tx*4 .. +3
    int ty = tid >> 4;                   // row group: rows ty*4 .. +3
    float acc[4][4] = {};
#pragma unroll 8
    for (int k = 0; k < 64; ++k) {
        float4 xv = *(const float4*)&xT[k * 68 + ty * 4];
        float4 wv = *(const float4*)&Wl[k * 64 + tx * 4];
        acc[0][0] = fmaf(xv.x, wv.x, acc[0][0]);
        acc[0][1] = fmaf(xv.x, wv.y, acc[0][1]);
        acc[0][2] = fmaf(xv.x, wv.z, acc[0][2]);
        acc[0][3] = fmaf(xv.x, wv.w, acc[0][3]);
        acc[1][0] = fmaf(xv.y, wv.x, acc[1][0]);
        acc[1][1] = fmaf(xv.y, wv.y, acc[1][1]);
        acc[1][2] = fmaf(xv.y, wv.z, acc[1][2]);
        acc[1][3] = fmaf(xv.y, wv.w, acc[1][3]);
        acc[2][0] = fmaf(xv.z, wv.x, acc[2][0]);
        acc[2][1] = fmaf(xv.z, wv.y, acc[2][1]);
        acc[2][2] = fmaf(xv.z, wv.z, acc[2][2]);
        acc[2][3] = fmaf(xv.z, wv.w, acc[2][3]);
        acc[3][0] = fmaf(xv.w, wv.x, acc[3][0]);
        acc[3][1] = fmaf(xv.w, wv.y, acc[3][1]);
        acc[3][2] = fmaf(xv.w, wv.z, acc[3][2]);
        acc[3][3] = fmaf(xv.w, wv.w, acc[3][3]);
    }
#pragma unroll
    for (int i = 0; i < 4; ++i) {
        int row = rowbase + ty * 4 + i;
        if (row < N) {
            float nr = norm[row];
            __half2 p0 = __floats2half2_rn(acc[i][0] * nr, acc[i][1] * nr);
            __half2 p1 = __floats2half2_rn(acc[i][2] * nr, acc[i][3] * nr);
            __half2* dst2 = (__half2*)(h2 + (size_t)row * 64 + tx * 4);
            dst2[0] = p0;
            dst2[1] = p1;
        }
    }
}

// K4 (sort-free aggregate, native-int LDS atomics): one 1024-thread block per
// 128-node bucket. Gathered fp16 values are converted to 2^20 fixed-point and
// accumulated with atomicAdd(int) -> native fire-and-forget ds_add_u32 (no
// CAS loop, no return dependency — this is what killed the round-1 float
// version). Accumulator split into X/Y planes [128][32]: bank = fl, 2
// lanes/bank = conflict-free. Per edge: 1 coalesced packed load + 1 shfl +
// one wave-coalesced 256B h2 gather + 2 ds_add. No sort, no CSR round-trip.
__global__ __launch_bounds__(1024)
void k_agg(const int* __restrict__ cursor, const unsigned* __restrict__ packed,
           const __half* __restrict__ h2, const float* __restrict__ norm,
           const float* __restrict__ bias, float* __restrict__ out) {
    __shared__ int sx[128 * 32];         // feature 2*fl   (16 KB)
    __shared__ int sy[128 * 32];         // feature 2*fl+1 (16 KB)
    int b = blockIdx.x, tid = threadIdx.x;
    for (int i = tid; i < 128 * 32; i += 1024) { sx[i] = 0; sy[i] = 0; }
    __syncthreads();
    int beg = b * CAP;
    int m = cursor[b] - beg;             // edges in this bucket
    int wave = tid >> 6, lane = tid & 63;
    int half = lane >> 5, fl = lane & 31;
    const __half2* h2v = (const __half2*)h2;   // row stride 32 (128B rows)
    constexpr float SCALE = 1048576.0f;        // 2^20
    for (int cbase = wave * 64; cbase < m; cbase += 1024) {
        int window = m - cbase;
        if (window >= 64) {
            unsigned pkreg = packed[beg + cbase + lane];
#pragma unroll 8
            for (int i = 0; i < 32; ++i) {
                unsigned pk = (unsigned)__shfl((int)pkreg, 2 * i + half, 64);
                int s = pk & 0xFFFF;
                int d = (pk >> 16) & 127;
                float2 v = __half22float2(h2v[s * 32 + fl]);
                atomicAdd(&sx[d * 32 + fl], __float2int_rn(v.x * SCALE));
                atomicAdd(&sy[d * 32 + fl], __float2int_rn(v.y * SCALE));
            }
        } else {
            unsigned pkreg = (cbase + lane < m) ? packed[beg + cbase + lane] : 0u;
            int npair = (window + 1) >> 1;
            for (int i = 0; i < npair; ++i) {
                int e = 2 * i + half;
                unsigned pk = (unsigned)__shfl((int)pkreg, e, 64);
                if (e < window) {
                    int s = pk & 0xFFFF;
                    int d = (pk >> 16) & 127;
                    float2 v = __half22float2(h2v[s * 32 + fl]);
                    atomicAdd(&sx[d * 32 + fl], __float2int_rn(v.x * SCALE));
                    atomicAdd(&sy[d * 32 + fl], __float2int_rn(v.y * SCALE));
                }
            }
        }
    }
    __syncthreads();
    // epilogue: thread -> (node r = tid>>3, feature block f0 = (tid&7)*8)
    int r = tid >> 3;
    int f0 = (tid & 7) * 8;
    int node = b * 128 + r;
    if (node < N) {
        float nrm = norm[node] * (1.0f / SCALE);
        float vals[8];
#pragma unroll
        for (int k = 0; k < 8; ++k) {
            int f = f0 + k;
            int acc = (f & 1) ? sy[r * 32 + (f >> 1)] : sx[r * 32 + (f >> 1)];
            float v = (float)acc * nrm + bias[f];
            vals[k] = fmaxf(v, 0.0f) + log1pf(expf(-fabsf(v)));
        }
        float4* o = (float4*)(out + node * 64 + f0);
        o[0] = make_float4(vals[0], vals[1], vals[2], vals[3]);
        o[1] = make_float4(vals[4], vals[5], vals[6], vals[7]);
    }
}

extern "C" void kernel_launch(void* const* d_in, const int* in_sizes, int n_in,
                              void* d_out, int out_size, void* d_ws, size_t ws_size,
                              hipStream_t stream) {
    // inputs: t(f32,1), x(f32,N*D), weight(f32,D*D), bias(f32,D), src(i32,E), dst(i32,E)
    const float* x    = (const float*)d_in[1];
    const float* W    = (const float*)d_in[2];
    const float* bias = (const float*)d_in[3];
    const int* src = (const int*)d_in[4];
    const int* dst = (const int*)d_in[5];
    float* out = (float*)d_out;

    // workspace layout (~13.8 MB; poisoned every call — every buffer is fully
    // written before it is read: cursor by k_init, packed windows only read
    // up to cursor[b], norm by k_norm, h2 by k_gemm)
    char* ws = (char*)d_ws;
    __half*   h2     = (__half*)(ws);                   // N*D*2       = 6.4 MB
    unsigned* packed = (unsigned*)(ws + 6400000);       // NBUCK*CAP*4 = 7.21 MB
    float*    norm   = (float*)(ws + 13606912);         // N*4
    int*      cursor = (int*)(ws + 13806912);           // NBUCK*4

    k_init  <<<1, 512, 0, stream>>>(cursor);
    k_bucket<<<BBLOCKS, BTHREADS, 0, stream>>>(src, dst, cursor, packed);
    k_norm  <<<NBUCK, 256, 0, stream>>>(cursor, packed, norm);
    k_gemm  <<<(N + 63) / 64, 256, 0, stream>>>(x, W, norm, h2);
    k_agg   <<<NBUCK, 1024, 0, stream>>>(cursor, packed, h2, norm, bias, out);
}

// Round 6
// 149.368 us; speedup vs baseline: 1.4809x; 1.1823x over previous
//
#include <hip/hip_runtime.h>
#include <hip/hip_fp16.h>

constexpr int N = 50000;        // nodes
constexpr int D = 64;           // feature dim
constexpr int E = 1600000;      // edges
constexpr int NBUCK = (N + 127) / 128;   // 391 buckets of 128 nodes (dst>>7)
constexpr int CAP = 4608;                // bucket window capacity (mean 4092)
constexpr int BTHREADS = 1024;           // was 512: 2 blocks/CU -> 32 waves/CU (100% occ)
constexpr int BBLOCKS = 512;             // 2 blocks/CU exactly
constexpr int EPB = E / BBLOCKS;         // 3125 edges per block (exact)
constexpr int CPT = (EPB + BTHREADS - 1) / BTHREADS;  // 4

// ---------------------------------------------------------------------------
// K0: init per-bucket window cursors (cursor[b] = b*CAP)
__global__ void k_init(int* __restrict__ cursor) {
    int t = threadIdx.x;
    if (t < NBUCK) cursor[t] = t * CAP;
}

// K1: privatized counting-sort scatter -> fixed-capacity bucket windows.
// packed = dst<<16 | src (both < 65536); bucket = packed>>23.
// Round-6 change: 1024 threads (same 512 blocks, same LDS) — round-4/5
// counters showed 37% occupancy + 1.9% VALUBusy (latency-bound at 16
// waves/CU). 1024 thr -> 32 waves/CU and 4-deep (was 7) per-thread chains.
__global__ __launch_bounds__(1024)
void k_bucket(const int* __restrict__ src, const int* __restrict__ dst,
              int* __restrict__ cursor, unsigned* __restrict__ packed) {
    __shared__ int lh[NBUCK];
    __shared__ int scanI[NBUCK];         // inclusive prefix over buckets
    __shared__ int wsum[16];             // 16 waves now
    __shared__ int lb[NBUCK];
    __shared__ unsigned stage[EPB];      // 12.5 KB
    int tid = threadIdx.x;
    if (tid < NBUCK) lh[tid] = 0;
    __syncthreads();
    int base_e = blockIdx.x * EPB;
    unsigned pk[CPT];
    int bn[CPT], rk[CPT];
#pragma unroll
    for (int i = 0; i < CPT; ++i) {
        int idx = i * BTHREADS + tid;
        if (idx < EPB) {
            int e = base_e + idx;
            int d = dst[e];
            int s = src[e];
            bn[i] = d >> 7;
            pk[i] = ((unsigned)d << 16) | (unsigned)s;
            rk[i] = atomicAdd(&lh[bn[i]], 1);
        } else bn[i] = -1;
    }
    __syncthreads();
    // hierarchical inclusive scan of lh[0..NBUCK) into scanI
    int w = tid >> 6, l = tid & 63;
    int v = (tid < NBUCK) ? lh[tid] : 0;
    for (int off = 1; off < 64; off <<= 1) {
        int t = __shfl_up(v, off, 64);
        if (l >= off) v += t;
    }
    if (tid < NBUCK) scanI[tid] = v;
    if (l == 63) wsum[w] = v;
    __syncthreads();
    if (tid < 64) {                      // wave 0 scans the 16 wave sums
        int s = (tid < 16) ? wsum[tid] : 0;
        for (int off = 1; off < 16; off <<= 1) {
            int t = __shfl_up(s, off, 64);
            if (tid >= off) s += t;
        }
        if (tid < 16) wsum[tid] = s;
    }
    __syncthreads();
    if (tid < NBUCK && w > 0) scanI[tid] += wsum[w - 1];
    if (tid < NBUCK) {
        int c = lh[tid];
        lb[tid] = c ? atomicAdd(&cursor[tid], c) : 0;   // one global atomic/bucket/block
    }
    __syncthreads();
#pragma unroll
    for (int i = 0; i < CPT; ++i) {
        if (bn[i] >= 0) {
            int eb = (bn[i] == 0) ? 0 : scanI[bn[i] - 1];
            stage[eb + rk[i]] = pk[i];   // LDS scatter into bucket-sorted order
        }
    }
    __syncthreads();
    for (int j = tid; j < EPB; j += BTHREADS) {
        unsigned vv = stage[j];
        int bk = vv >> 23;               // dst>>7
        int eb = (bk == 0) ? 0 : scanI[bk - 1];
        packed[lb[bk] + (j - eb)] = vv;  // contiguous within each chunk
    }
}

// K2: one block (1024 thr) per 128-node bucket — LDS hist + single-wave shfl
// scan -> rowptr/rowend/norm; fill node-sorted u16 src into LDS stage, then
// coalesced uint copy-out to the bucket's CSR window.
// (verified round-0/3 version, unchanged)
__global__ void k_csr(const int* __restrict__ cursor, const unsigned* __restrict__ packed,
                      unsigned short* __restrict__ csr, int* __restrict__ rowptr,
                      int* __restrict__ rowend, float* __restrict__ norm) {
    __shared__ int cnt[128];
    __shared__ int sm[128];              // inclusive prefix over 128 bins
    __shared__ int cur[128];
    __shared__ unsigned short stage[CAP];   // 9 KB
    int b = blockIdx.x, tid = threadIdx.x;
    if (tid < 128) cnt[tid] = 0;
    __syncthreads();
    int beg = b * CAP;
    int m = cursor[b] - beg;                // edges in this bucket
    for (int j = tid; j < m; j += 1024)
        atomicAdd(&cnt[(packed[beg + j] >> 16) & 127], 1);
    __syncthreads();
    if (tid < 64) {                      // wave 0: 2 bins/lane inclusive scan
        int a = cnt[2 * tid], c1 = cnt[2 * tid + 1];
        int s = a + c1;
        for (int off = 1; off < 64; off <<= 1) {
            int t = __shfl_up(s, off, 64);
            if (tid >= off) s += t;
        }
        sm[2 * tid + 1] = s;             // incl(2t+1)
        sm[2 * tid] = s - c1;            // incl(2t)
    }
    __syncthreads();
    if (tid < 128) {
        int incl = sm[tid];
        int excl = incl - cnt[tid];
        int node = b * 128 + tid;
        if (node < N) {
            rowptr[node] = beg + excl;
            rowend[node] = beg + incl;
            norm[node] = cnt[tid] ? rsqrtf((float)cnt[tid]) : 0.0f;
        }
        cur[tid] = excl;                 // local offset within stage
    }
    __syncthreads();
    for (int j = tid; j < m; j += 1024) {
        unsigned p = packed[beg + j];
        int slot = atomicAdd(&cur[(p >> 16) & 127], 1);
        stage[slot] = (unsigned short)(p & 0xFFFFu);
    }
    __syncthreads();
    unsigned* du = (unsigned*)(csr + beg);  // beg even, base 4B-aligned
    const unsigned* su = (const unsigned*)stage;
    int mu = m >> 1;
    for (int k = tid; k < mu; k += 1024) du[k] = su[k];
    if ((m & 1) && tid == 0) csr[beg + m - 1] = stage[m - 1];
}

// K3 (register-tiled LDS GEMM): h2[row][d] = (x@W)[row][d] * norm[row], fp16.
// (verified round-3 version, unchanged)
__global__ __launch_bounds__(256)
void k_gemm(const float* __restrict__ x, const float* __restrict__ W,
            const float* __restrict__ norm, __half* __restrict__ h2) {
    __shared__ float xT[64 * 68];        // xT[k*68 + r] = x[rowbase+r][k]  (17 KB)
    __shared__ float Wl[64 * 64];        // Wl[k*64 + d] = W[k][d]          (16 KB)
    int tid = threadIdx.x;
    int rowbase = blockIdx.x * 64;
    {
        const float4* W4 = (const float4*)W;
        float4* Wl4 = (float4*)Wl;
#pragma unroll
        for (int i = 0; i < 4; ++i)
            Wl4[i * 256 + tid] = W4[i * 256 + tid];
    }
    {
        int rr = tid >> 2;
        int c0 = (tid & 3) * 16;
        int row = rowbase + rr;
        if (row >= N) row = N - 1;       // clamp (stores are guarded)
        const float4* xr = (const float4*)(x + (size_t)row * 64 + c0);
#pragma unroll
        for (int i = 0; i < 4; ++i) {
            float4 v = xr[i];
            int c = c0 + i * 4;
            xT[(c + 0) * 68 + rr] = v.x;
            xT[(c + 1) * 68 + rr] = v.y;
            xT[(c + 2) * 68 + rr] = v.z;
            xT[(c + 3) * 68 + rr] = v.w;
        }
    }
    __syncthreads();
    int tx = tid & 15;                   // col group: cols tx*4 .. +3
    int ty = tid >> 4;                   // row group: rows ty*4 .. +3
    float acc[4][4] = {};
#pragma unroll 8
    for (int k = 0; k < 64; ++k) {
        float4 xv = *(const float4*)&xT[k * 68 + ty * 4];
        float4 wv = *(const float4*)&Wl[k * 64 + tx * 4];
        acc[0][0] = fmaf(xv.x, wv.x, acc[0][0]);
        acc[0][1] = fmaf(xv.x, wv.y, acc[0][1]);
        acc[0][2] = fmaf(xv.x, wv.z, acc[0][2]);
        acc[0][3] = fmaf(xv.x, wv.w, acc[0][3]);
        acc[1][0] = fmaf(xv.y, wv.x, acc[1][0]);
        acc[1][1] = fmaf(xv.y, wv.y, acc[1][1]);
        acc[1][2] = fmaf(xv.y, wv.z, acc[1][2]);
        acc[1][3] = fmaf(xv.y, wv.w, acc[1][3]);
        acc[2][0] = fmaf(xv.z, wv.x, acc[2][0]);
        acc[2][1] = fmaf(xv.z, wv.y, acc[2][1]);
        acc[2][2] = fmaf(xv.z, wv.z, acc[2][2]);
        acc[2][3] = fmaf(xv.z, wv.w, acc[2][3]);
        acc[3][0] = fmaf(xv.w, wv.x, acc[3][0]);
        acc[3][1] = fmaf(xv.w, wv.y, acc[3][1]);
        acc[3][2] = fmaf(xv.w, wv.z, acc[3][2]);
        acc[3][3] = fmaf(xv.w, wv.w, acc[3][3]);
    }
#pragma unroll
    for (int i = 0; i < 4; ++i) {
        int row = rowbase + ty * 4 + i;
        if (row < N) {
            float nr = norm[row];
            __half2 p0 = __floats2half2_rn(acc[i][0] * nr, acc[i][1] * nr);
            __half2 p1 = __floats2half2_rn(acc[i][2] * nr, acc[i][3] * nr);
            __half2* dst2 = (__half2*)(h2 + (size_t)row * 64 + tx * 4);
            dst2[0] = p0;
            dst2[1] = p1;
        }
    }
}

// K4: fused aggregate + dst-norm + bias + softplus.
// One wave per node (12500 blocks x 4 waves = 50K waves: the TLP that makes
// the latency-bound gather fast — round-5's 391-block variant proved the
// 8x-fewer-waves shape is 2x slower). Edge indices captured up-front;
// gather loop gets src via __shfl. (verified round-3 version, unchanged)
__global__ void k_aggregate(const int* __restrict__ rowptr, const int* __restrict__ rowend,
                            const unsigned short* __restrict__ csr,
                            const __half* __restrict__ h2, const float* __restrict__ norm,
                            const float* __restrict__ bias, float* __restrict__ out) {
    int node = blockIdx.x * 4 + (threadIdx.x >> 6);
    int lane = threadIdx.x & 63;
    int half = lane >> 5;          // which edge of the pair
    int fl = lane & 31;            // feature-pair index (features 2fl, 2fl+1)
    const __half2* h2v = (const __half2*)h2;   // row stride 32
    int beg = rowptr[node];
    int end = rowend[node];
    int deg = end - beg;
    int myidx = (beg + lane < end) ? (int)csr[beg + lane] : 0;
    int window = deg < 64 ? deg : 64;   // wave-uniform
    int npair = window >> 1;
    float ax = 0.0f, ay = 0.0f, bx = 0.0f, by = 0.0f;
    int p = 0;
    for (; p + 7 < npair; p += 8) {          // 16 edges per iteration, 8 loads in flight
        int s0 = __shfl(myidx, 2 * p + half, 64);
        int s1 = __shfl(myidx, 2 * p + 2 + half, 64);
        int s2 = __shfl(myidx, 2 * p + 4 + half, 64);
        int s3 = __shfl(myidx, 2 * p + 6 + half, 64);
        int s4 = __shfl(myidx, 2 * p + 8 + half, 64);
        int s5 = __shfl(myidx, 2 * p + 10 + half, 64);
        int s6 = __shfl(myidx, 2 * p + 12 + half, 64);
        int s7 = __shfl(myidx, 2 * p + 14 + half, 64);
        float2 v0 = __half22float2(h2v[s0 * 32 + fl]);
        float2 v1 = __half22float2(h2v[s1 * 32 + fl]);
        float2 v2 = __half22float2(h2v[s2 * 32 + fl]);
        float2 v3 = __half22float2(h2v[s3 * 32 + fl]);
        float2 v4 = __half22float2(h2v[s4 * 32 + fl]);
        float2 v5 = __half22float2(h2v[s5 * 32 + fl]);
        float2 v6 = __half22float2(h2v[s6 * 32 + fl]);
        float2 v7 = __half22float2(h2v[s7 * 32 + fl]);
        ax += (v0.x + v2.x) + (v4.x + v6.x);
        ay += (v0.y + v2.y) + (v4.y + v6.y);
        bx += (v1.x + v3.x) + (v5.x + v7.x);
        by += (v1.y + v3.y) + (v5.y + v7.y);
    }
    for (; p + 3 < npair; p += 4) {          // 8 edges per iteration
        int s0 = __shfl(myidx, 2 * p + half, 64);
        int s1 = __shfl(myidx, 2 * p + 2 + half, 64);
        int s2 = __shfl(myidx, 2 * p + 4 + half, 64);
        int s3 = __shfl(myidx, 2 * p + 6 + half, 64);
        float2 v0 = __half22float2(h2v[s0 * 32 + fl]);
        float2 v1 = __half22float2(h2v[s1 * 32 + fl]);
        float2 v2 = __half22float2(h2v[s2 * 32 + fl]);
        float2 v3 = __half22float2(h2v[s3 * 32 + fl]);
        ax += v0.x + v2.x;  ay += v0.y + v2.y;
        bx += v1.x + v3.x;  by += v1.y + v3.y;
    }
    for (; p < npair; ++p) {                 // pair tail (uniform trip count)
        int s = __shfl(myidx, 2 * p + half, 64);
        float2 v = __half22float2(h2v[s * 32 + fl]);
        ax += v.x;  ay += v.y;
    }
    if (window & 1) {                        // wave-uniform: all lanes shfl
        int s = __shfl(myidx, window - 1, 64);
        float2 v = __half22float2(h2v[s * 32 + fl]);
        if (half == 0) { ax += v.x;  ay += v.y; }
    }
    if (deg > 64) {                          // rare fallback, direct loads
        int j = beg + 64;
        for (; j + 1 < end; j += 2) {
            int s = csr[j + half];
            float2 v = __half22float2(h2v[s * 32 + fl]);
            ax += v.x;  ay += v.y;
        }
        if (j < end) {
            int s = csr[j];
            float2 v = __half22float2(h2v[s * 32 + fl]);
            if (half == 0) { ax += v.x;  ay += v.y; }
        }
    }
    ax += bx;  ay += by;
    ax += __shfl_xor(ax, 32, 64);            // combine the two half-waves
    ay += __shfl_xor(ay, 32, 64);
    if (half == 0) {
        float nrm = norm[node];
        float2 bs = ((const float2*)bias)[fl];
        float vx = ax * nrm + bs.x;
        float vy = ay * nrm + bs.y;
        float2 o;
        o.x = fmaxf(vx, 0.0f) + log1pf(expf(-fabsf(vx)));
        o.y = fmaxf(vy, 0.0f) + log1pf(expf(-fabsf(vy)));
        ((float2*)out)[node * 32 + fl] = o;
    }
}

extern "C" void kernel_launch(void* const* d_in, const int* in_sizes, int n_in,
                              void* d_out, int out_size, void* d_ws, size_t ws_size,
                              hipStream_t stream) {
    // inputs: t(f32,1), x(f32,N*D), weight(f32,D*D), bias(f32,D), src(i32,E), dst(i32,E)
    const float* x    = (const float*)d_in[1];
    const float* W    = (const float*)d_in[2];
    const float* bias = (const float*)d_in[3];
    const int* src = (const int*)d_in[4];
    const int* dst = (const int*)d_in[5];
    float* out = (float*)d_out;

    // workspace layout (~17.9 MB; poisoned every call — every buffer is
    // fully written before it is read)
    char* ws = (char*)d_ws;
    __half*         h2     = (__half*)(ws);                     // 6.4 MB
    unsigned*       packed = (unsigned*)(ws + 6400000);         // NBUCK*CAP*4 = 7.21 MB
    unsigned short* csr    = (unsigned short*)(ws + 13606912);  // NBUCK*CAP*2 = 3.6 MB
    int*            rowptr = (int*)(ws + 17210368);             // N*4
    int*            rowend = (int*)(ws + 17410368);             // N*4
    float*          norm   = (float*)(ws + 17610368);           // N*4
    int*            cursor = (int*)(ws + 17810368);             // NBUCK*4

    k_init     <<<1, 512, 0, stream>>>(cursor);
    k_bucket   <<<BBLOCKS, BTHREADS, 0, stream>>>(src, dst, cursor, packed);
    k_csr      <<<NBUCK, 1024, 0, stream>>>(cursor, packed, csr, rowptr, rowend, norm);
    k_gemm     <<<(N + 63) / 64, 256, 0, stream>>>(x, W, norm, h2);
    k_aggregate<<<(N + 3) / 4, 256, 0, stream>>>(rowptr, rowend, csr, h2, norm, bias, out);
}

// Round 7
// 142.640 us; speedup vs baseline: 1.5508x; 1.0472x over previous
//
#include <hip/hip_runtime.h>
#include <hip/hip_fp16.h>

constexpr int N = 50000;        // nodes
constexpr int D = 64;           // feature dim
constexpr int E = 1600000;      // edges
constexpr int NBUCK = (N + 127) / 128;   // 391 buckets of 128 nodes (dst>>7)
constexpr int CAP = 4608;                // bucket window capacity (mean 4092)
constexpr int BTHREADS = 1024;
constexpr int BBLOCKS = 256;             // was 512: bigger per-block chunks ->
                                         // copy-out segments 2x longer (64B)
constexpr int EPB = E / BBLOCKS;         // 6250 edges per block (exact)
constexpr int CPT = (EPB + BTHREADS - 1) / BTHREADS;  // 7

// ---------------------------------------------------------------------------
// K0: init per-bucket window cursors (cursor[b] = b*CAP)
__global__ void k_init(int* __restrict__ cursor) {
    int t = threadIdx.x;
    if (t < NBUCK) cursor[t] = t * CAP;
}

// K1: privatized counting-sort scatter -> fixed-capacity bucket windows.
// packed = dst<<16 | src (both < 65536); bucket = packed>>23.
// Round-7 change: 256 blocks x EPB=6250 (stage 25 KB). Round-6 proved the
// stage is not occupancy-bound (16 vs 32 waves/CU neutral), so we spend
// occupancy to double the copy-out chunk length (~16 edges = 64B): half the
// scattered segments per wave-store, half the 64B-line write amplification.
__global__ __launch_bounds__(1024)
void k_bucket(const int* __restrict__ src, const int* __restrict__ dst,
              int* __restrict__ cursor, unsigned* __restrict__ packed) {
    __shared__ int lh[NBUCK];
    __shared__ int scanI[NBUCK];         // inclusive prefix over buckets
    __shared__ int wsum[16];             // 16 waves
    __shared__ int lb[NBUCK];
    __shared__ unsigned stage[EPB];      // 25 KB
    int tid = threadIdx.x;
    if (tid < NBUCK) lh[tid] = 0;
    __syncthreads();
    int base_e = blockIdx.x * EPB;
    unsigned pk[CPT];
    int bn[CPT], rk[CPT];
#pragma unroll
    for (int i = 0; i < CPT; ++i) {
        int idx = i * BTHREADS + tid;
        if (idx < EPB) {
            int e = base_e + idx;
            int d = dst[e];
            int s = src[e];
            bn[i] = d >> 7;
            pk[i] = ((unsigned)d << 16) | (unsigned)s;
            rk[i] = atomicAdd(&lh[bn[i]], 1);
        } else bn[i] = -1;
    }
    __syncthreads();
    // hierarchical inclusive scan of lh[0..NBUCK) into scanI
    int w = tid >> 6, l = tid & 63;
    int v = (tid < NBUCK) ? lh[tid] : 0;
    for (int off = 1; off < 64; off <<= 1) {
        int t = __shfl_up(v, off, 64);
        if (l >= off) v += t;
    }
    if (tid < NBUCK) scanI[tid] = v;
    if (l == 63) wsum[w] = v;
    __syncthreads();
    if (tid < 64) {                      // wave 0 scans the 16 wave sums
        int s = (tid < 16) ? wsum[tid] : 0;
        for (int off = 1; off < 16; off <<= 1) {
            int t = __shfl_up(s, off, 64);
            if (tid >= off) s += t;
        }
        if (tid < 16) wsum[tid] = s;
    }
    __syncthreads();
    if (tid < NBUCK && w > 0) scanI[tid] += wsum[w - 1];
    if (tid < NBUCK) {
        int c = lh[tid];
        lb[tid] = c ? atomicAdd(&cursor[tid], c) : 0;   // one global atomic/bucket/block
    }
    __syncthreads();
#pragma unroll
    for (int i = 0; i < CPT; ++i) {
        if (bn[i] >= 0) {
            int eb = (bn[i] == 0) ? 0 : scanI[bn[i] - 1];
            stage[eb + rk[i]] = pk[i];   // LDS scatter into bucket-sorted order
        }
    }
    __syncthreads();
    for (int j = tid; j < EPB; j += BTHREADS) {
        unsigned vv = stage[j];
        int bk = vv >> 23;               // dst>>7
        int eb = (bk == 0) ? 0 : scanI[bk - 1];
        packed[lb[bk] + (j - eb)] = vv;  // contiguous within each chunk
    }
}

// K2 (single-pass CSR): one 1024-thr block per 128-node bucket. The rank
// returned by the histogram atomicAdd IS the stable slot (mechanism verified
// in round-4's k_fused phase 1) — deletes the second read of packed and the
// second 1.6M-atomic pass of the old two-pass version. Outputs identical:
// csr/rowptr/rowend/norm.
__global__ __launch_bounds__(1024)
void k_csr(const int* __restrict__ cursor, const unsigned* __restrict__ packed,
           unsigned short* __restrict__ csr, int* __restrict__ rowptr,
           int* __restrict__ rowend, float* __restrict__ norm) {
    __shared__ int cnt[128];
    __shared__ int rowoff[128];          // exclusive prefix over 128 bins
    __shared__ unsigned short stage[CAP];   // 9 KB node-sorted src list
    int b = blockIdx.x, tid = threadIdx.x;
    if (tid < 128) cnt[tid] = 0;
    __syncthreads();
    int beg = b * CAP;
    int m = cursor[b] - beg;             // edges in this bucket (<= CAP)
    unsigned pk[5];
    int rk[5], dd[5];
#pragma unroll
    for (int it = 0; it < 5; ++it) {     // ceil(CAP/1024) = 5
        int j = it * 1024 + tid;
        if (j < m) {
            unsigned p = packed[beg + j];
            int d = (p >> 16) & 127;
            dd[it] = d;
            pk[it] = p;
            rk[it] = atomicAdd(&cnt[d], 1);   // rank = stable slot
        } else dd[it] = -1;
    }
    __syncthreads();
    if (tid < 64) {                      // wave 0: 2 bins/lane inclusive scan
        int a = cnt[2 * tid], c1 = cnt[2 * tid + 1];
        int s = a + c1;
        for (int off = 1; off < 64; off <<= 1) {
            int t = __shfl_up(s, off, 64);
            if (tid >= off) s += t;
        }
        rowoff[2 * tid + 1] = s - c1;    // excl(2t+1)
        rowoff[2 * tid]     = s - c1 - a;    // excl(2t)
    }
    __syncthreads();
    if (tid < 128) {
        int excl = rowoff[tid];
        int node = b * 128 + tid;
        if (node < N) {
            rowptr[node] = beg + excl;
            rowend[node] = beg + excl + cnt[tid];
            norm[node] = cnt[tid] ? rsqrtf((float)cnt[tid]) : 0.0f;
        }
    }
    __syncthreads();
#pragma unroll
    for (int it = 0; it < 5; ++it)
        if (dd[it] >= 0)
            stage[rowoff[dd[it]] + rk[it]] = (unsigned short)(pk[it] & 0xFFFFu);
    __syncthreads();
    unsigned* du = (unsigned*)(csr + beg);  // beg even, base 4B-aligned
    const unsigned* su = (const unsigned*)stage;
    int mu = m >> 1;
    for (int k = tid; k < mu; k += 1024) du[k] = su[k];
    if ((m & 1) && tid == 0) csr[beg + m - 1] = stage[m - 1];
}

// K3 (register-tiled LDS GEMM): h2[row][d] = (x@W)[row][d] * norm[row], fp16.
// (verified round-3 version, unchanged)
__global__ __launch_bounds__(256)
void k_gemm(const float* __restrict__ x, const float* __restrict__ W,
            const float* __restrict__ norm, __half* __restrict__ h2) {
    __shared__ float xT[64 * 68];        // xT[k*68 + r] = x[rowbase+r][k]  (17 KB)
    __shared__ float Wl[64 * 64];        // Wl[k*64 + d] = W[k][d]          (16 KB)
    int tid = threadIdx.x;
    int rowbase = blockIdx.x * 64;
    {
        const float4* W4 = (const float4*)W;
        float4* Wl4 = (float4*)Wl;
#pragma unroll
        for (int i = 0; i < 4; ++i)
            Wl4[i * 256 + tid] = W4[i * 256 + tid];
    }
    {
        int rr = tid >> 2;
        int c0 = (tid & 3) * 16;
        int row = rowbase + rr;
        if (row >= N) row = N - 1;       // clamp (stores are guarded)
        const float4* xr = (const float4*)(x + (size_t)row * 64 + c0);
#pragma unroll
        for (int i = 0; i < 4; ++i) {
            float4 v = xr[i];
            int c = c0 + i * 4;
            xT[(c + 0) * 68 + rr] = v.x;
            xT[(c + 1) * 68 + rr] = v.y;
            xT[(c + 2) * 68 + rr] = v.z;
            xT[(c + 3) * 68 + rr] = v.w;
        }
    }
    __syncthreads();
    int tx = tid & 15;                   // col group: cols tx*4 .. +3
    int ty = tid >> 4;                   // row group: rows ty*4 .. +3
    float acc[4][4] = {};
#pragma unroll 8
    for (int k = 0; k < 64; ++k) {
        float4 xv = *(const float4*)&xT[k * 68 + ty * 4];
        float4 wv = *(const float4*)&Wl[k * 64 + tx * 4];
        acc[0][0] = fmaf(xv.x, wv.x, acc[0][0]);
        acc[0][1] = fmaf(xv.x, wv.y, acc[0][1]);
        acc[0][2] = fmaf(xv.x, wv.z, acc[0][2]);
        acc[0][3] = fmaf(xv.x, wv.w, acc[0][3]);
        acc[1][0] = fmaf(xv.y, wv.x, acc[1][0]);
        acc[1][1] = fmaf(xv.y, wv.y, acc[1][1]);
        acc[1][2] = fmaf(xv.y, wv.z, acc[1][2]);
        acc[1][3] = fmaf(xv.y, wv.w, acc[1][3]);
        acc[2][0] = fmaf(xv.z, wv.x, acc[2][0]);
        acc[2][1] = fmaf(xv.z, wv.y, acc[2][1]);
        acc[2][2] = fmaf(xv.z, wv.z, acc[2][2]);
        acc[2][3] = fmaf(xv.z, wv.w, acc[2][3]);
        acc[3][0] = fmaf(xv.w, wv.x, acc[3][0]);
        acc[3][1] = fmaf(xv.w, wv.y, acc[3][1]);
        acc[3][2] = fmaf(xv.w, wv.z, acc[3][2]);
        acc[3][3] = fmaf(xv.w, wv.w, acc[3][3]);
    }
#pragma unroll
    for (int i = 0; i < 4; ++i) {
        int row = rowbase + ty * 4 + i;
        if (row < N) {
            float nr = norm[row];
            __half2 p0 = __floats2half2_rn(acc[i][0] * nr, acc[i][1] * nr);
            __half2 p1 = __floats2half2_rn(acc[i][2] * nr, acc[i][3] * nr);
            __half2* dst2 = (__half2*)(h2 + (size_t)row * 64 + tx * 4);
            dst2[0] = p0;
            dst2[1] = p1;
        }
    }
}

// K4: fused aggregate + dst-norm + bias + softplus.
// One wave per node (12500 blocks x 4 waves = 50K waves of TLP — round-5's
// 391-block variant proved fewer waves is 2x slower). Edge indices captured
// up-front; gather loop gets src via __shfl. (verified round-3 version)
__global__ void k_aggregate(const int* __restrict__ rowptr, const int* __restrict__ rowend,
                            const unsigned short* __restrict__ csr,
                            const __half* __restrict__ h2, const float* __restrict__ norm,
                            const float* __restrict__ bias, float* __restrict__ out) {
    int node = blockIdx.x * 4 + (threadIdx.x >> 6);
    int lane = threadIdx.x & 63;
    int half = lane >> 5;          // which edge of the pair
    int fl = lane & 31;            // feature-pair index (features 2fl, 2fl+1)
    const __half2* h2v = (const __half2*)h2;   // row stride 32
    int beg = rowptr[node];
    int end = rowend[node];
    int deg = end - beg;
    int myidx = (beg + lane < end) ? (int)csr[beg + lane] : 0;
    int window = deg < 64 ? deg : 64;   // wave-uniform
    int npair = window >> 1;
    float ax = 0.0f, ay = 0.0f, bx = 0.0f, by = 0.0f;
    int p = 0;
    for (; p + 7 < npair; p += 8) {          // 16 edges per iteration, 8 loads in flight
        int s0 = __shfl(myidx, 2 * p + half, 64);
        int s1 = __shfl(myidx, 2 * p + 2 + half, 64);
        int s2 = __shfl(myidx, 2 * p + 4 + half, 64);
        int s3 = __shfl(myidx, 2 * p + 6 + half, 64);
        int s4 = __shfl(myidx, 2 * p + 8 + half, 64);
        int s5 = __shfl(myidx, 2 * p + 10 + half, 64);
        int s6 = __shfl(myidx, 2 * p + 12 + half, 64);
        int s7 = __shfl(myidx, 2 * p + 14 + half, 64);
        float2 v0 = __half22float2(h2v[s0 * 32 + fl]);
        float2 v1 = __half22float2(h2v[s1 * 32 + fl]);
        float2 v2 = __half22float2(h2v[s2 * 32 + fl]);
        float2 v3 = __half22float2(h2v[s3 * 32 + fl]);
        float2 v4 = __half22float2(h2v[s4 * 32 + fl]);
        float2 v5 = __half22float2(h2v[s5 * 32 + fl]);
        float2 v6 = __half22float2(h2v[s6 * 32 + fl]);
        float2 v7 = __half22float2(h2v[s7 * 32 + fl]);
        ax += (v0.x + v2.x) + (v4.x + v6.x);
        ay += (v0.y + v2.y) + (v4.y + v6.y);
        bx += (v1.x + v3.x) + (v5.x + v7.x);
        by += (v1.y + v3.y) + (v5.y + v7.y);
    }
    for (; p + 3 < npair; p += 4) {          // 8 edges per iteration
        int s0 = __shfl(myidx, 2 * p + half, 64);
        int s1 = __shfl(myidx, 2 * p + 2 + half, 64);
        int s2 = __shfl(myidx, 2 * p + 4 + half, 64);
        int s3 = __shfl(myidx, 2 * p + 6 + half, 64);
        float2 v0 = __half22float2(h2v[s0 * 32 + fl]);
        float2 v1 = __half22float2(h2v[s1 * 32 + fl]);
        float2 v2 = __half22float2(h2v[s2 * 32 + fl]);
        float2 v3 = __half22float2(h2v[s3 * 32 + fl]);
        ax += v0.x + v2.x;  ay += v0.y + v2.y;
        bx += v1.x + v3.x;  by += v1.y + v3.y;
    }
    for (; p < npair; ++p) {                 // pair tail (uniform trip count)
        int s = __shfl(myidx, 2 * p + half, 64);
        float2 v = __half22float2(h2v[s * 32 + fl]);
        ax += v.x;  ay += v.y;
    }
    if (window & 1) {                        // wave-uniform: all lanes shfl
        int s = __shfl(myidx, window - 1, 64);
        float2 v = __half22float2(h2v[s * 32 + fl]);
        if (half == 0) { ax += v.x;  ay += v.y; }
    }
    if (deg > 64) {                          // rare fallback, direct loads
        int j = beg + 64;
        for (; j + 1 < end; j += 2) {
            int s = csr[j + half];
            float2 v = __half22float2(h2v[s * 32 + fl]);
            ax += v.x;  ay += v.y;
        }
        if (j < end) {
            int s = csr[j];
            float2 v = __half22float2(h2v[s * 32 + fl]);
            if (half == 0) { ax += v.x;  ay += v.y; }
        }
    }
    ax += bx;  ay += by;
    ax += __shfl_xor(ax, 32, 64);            // combine the two half-waves
    ay += __shfl_xor(ay, 32, 64);
    if (half == 0) {
        float nrm = norm[node];
        float2 bs = ((const float2*)bias)[fl];
        float vx = ax * nrm + bs.x;
        float vy = ay * nrm + bs.y;
        float2 o;
        o.x = fmaxf(vx, 0.0f) + log1pf(expf(-fabsf(vx)));
        o.y = fmaxf(vy, 0.0f) + log1pf(expf(-fabsf(vy)));
        ((float2*)out)[node * 32 + fl] = o;
    }
}

extern "C" void kernel_launch(void* const* d_in, const int* in_sizes, int n_in,
                              void* d_out, int out_size, void* d_ws, size_t ws_size,
                              hipStream_t stream) {
    // inputs: t(f32,1), x(f32,N*D), weight(f32,D*D), bias(f32,D), src(i32,E), dst(i32,E)
    const float* x    = (const float*)d_in[1];
    const float* W    = (const float*)d_in[2];
    const float* bias = (const float*)d_in[3];
    const int* src = (const int*)d_in[4];
    const int* dst = (const int*)d_in[5];
    float* out = (float*)d_out;

    // workspace layout (~17.9 MB; poisoned every call — every buffer is
    // fully written before it is read)
    char* ws = (char*)d_ws;
    __half*         h2     = (__half*)(ws);                     // 6.4 MB
    unsigned*       packed = (unsigned*)(ws + 6400000);         // NBUCK*CAP*4 = 7.21 MB
    unsigned short* csr    = (unsigned short*)(ws + 13606912);  // NBUCK*CAP*2 = 3.6 MB
    int*            rowptr = (int*)(ws + 17210368);             // N*4
    int*            rowend = (int*)(ws + 17410368);             // N*4
    float*          norm   = (float*)(ws + 17610368);           // N*4
    int*            cursor = (int*)(ws + 17810368);             // NBUCK*4

    k_init     <<<1, 512, 0, stream>>>(cursor);
    k_bucket   <<<BBLOCKS, BTHREADS, 0, stream>>>(src, dst, cursor, packed);
    k_csr      <<<NBUCK, 1024, 0, stream>>>(cursor, packed, csr, rowptr, rowend, norm);
    k_gemm     <<<(N + 63) / 64, 256, 0, stream>>>(x, W, norm, h2);
    k_aggregate<<<(N + 3) / 4, 256, 0, stream>>>(rowptr, rowend, csr, h2, norm, bias, out);
}